// Round 8
// baseline (74.170 us; speedup 1.0000x reference)
//
#include <hip/hip_runtime.h>
#include <hip/hip_bf16.h>
#include <math.h>

#define HS 8
#define E 12
#define NA 20
#define KC 4

typedef float f32x4 __attribute__((ext_vector_type(4)));
typedef short short8 __attribute__((ext_vector_type(8)));

// ---------------- Precomputed, batch-independent tables ----------------
__device__ float g_ET[4 * 54 * 54];   // exp(q_h(c1)·k_h(c2)/sqrt(3))
__device__ float g_VT[4 * 54 * 4];    // per-head v vectors (v0,v1,v2,1)
__device__ float g_abias[NA * 32];    // per-action folded score bias
__device__ __align__(16) short g_gsB[4 * 64 * 16];    // gs_w1 B-frags [t][lane][8hi,8lo]
__device__ __align__(16) short g_dpB[8 * 64 * 16];    // dp_w1 B-frags [s*4+t][lane]
__device__ __align__(16) short g_ctxB[16 * 64 * 16];  // ctx W' B-frags [s*8+tt][lane], K=64
__device__ __align__(16) short g_WtB[8 * 64 * 16];    // folded Wt B-frags [s*2+t][lane]
// Inter-kernel features: [B][32] = attsum/len(12), enemy(12), 1/len, pads=0 (BSS zero)
__device__ __align__(16) float g_feat[65536 * 32];

__device__ __forceinline__ short bfh(float f) {
    return (short)__bfloat16_as_ushort(__float2bfloat16(f));
}
__device__ __forceinline__ void split_bf16(float f, short& hi, short& lo) {
    hi = bfh(f);
    float fh = __uint_as_float(((unsigned)(unsigned short)hi) << 16);
    lo = bfh(f - fh);
}
__device__ __forceinline__ void split8(const float* x, short8& hi, short8& lo) {
#pragma unroll
    for (int j = 0; j < 8; ++j) {
        short h, l;
        split_bf16(x[j], h, l);
        hi[j] = h; lo[j] = l;
    }
}

#define MFMA(a, b, c) __builtin_amdgcn_mfma_f32_16x16x32_bf16(a, b, c, 0, 0, 0)

__device__ __forceinline__ f32x4 mfma3v(short8 ah, short8 al, short8 bh, short8 bl,
                                        f32x4 c) {
    c = MFMA(ah, bh, c);
    c = MFMA(ah, bl, c);
    c = MFMA(al, bh, c);
    return c;
}

// ctx B'[k][hid], k in 0..63: out_w folded into k<12, invlen feat at k=24,
// gs hidden out at k=32..37, dp at 38..43 (post layer-2 feats), zeros elsewhere.
__device__ float ctxw(int hid, int k, const float* ctx_w1, const float* out_w,
                      const float* out_b) {
    if (k < 12) {
        float s = 0.f;
        for (int i = 0; i < 12; ++i) s += ctx_w1[hid * 36 + i] * out_w[i * 12 + k];
        return s;
    } else if (k < 24) {
        return ctx_w1[hid * 36 + k];
    } else if (k == 24) {
        float s = 0.f;
        for (int i = 0; i < 12; ++i) s += ctx_w1[hid * 36 + i] * out_b[i];
        return 8.f * s;
    } else if (k < 32) {
        return 0.f;
    } else if (k < 44) {
        return ctx_w1[hid * 36 + 24 + (k - 32)];
    }
    return 0.f;
}

__global__ void precompute_kernel(const float* __restrict__ card_emb,
                                  const int* __restrict__ aci,
                                  const float* __restrict__ ctx_w2,
                                  const float* __restrict__ ctx_b2,
                                  const float* __restrict__ sc_w1,
                                  const float* __restrict__ sc_b1,
                                  const float* __restrict__ in_w,
                                  const float* __restrict__ in_b,
                                  const float* __restrict__ ctx_w1,
                                  const float* __restrict__ dp_w1,
                                  const float* __restrict__ gs_w1,
                                  const float* __restrict__ out_w,
                                  const float* __restrict__ out_b) {
    const int O_ET = 11664, O_VT = O_ET + 216, O_GS = O_VT + 2048, O_DP = O_GS + 4096;
    const int O_CX = O_DP + 8192, O_WT = O_CX + 4096, O_AB = O_WT + 640;
    int t = blockIdx.x * 256 + threadIdx.x;
    if (t < O_ET) {
        int h = t / 2916, rem = t % 2916;
        int c1 = rem / 54, c2 = rem % 54;
        float s = 0.f;
#pragma unroll
        for (int d = 0; d < 3; ++d) {
            float q = in_b[h * 3 + d], k = in_b[12 + h * 3 + d];
            for (int j = 0; j < 12; ++j) {
                q += in_w[(h * 3 + d) * 12 + j] * card_emb[c1 * 12 + j];
                k += in_w[(12 + h * 3 + d) * 12 + j] * card_emb[c2 * 12 + j];
            }
            s += q * k;
        }
        g_ET[t] = expf(s * 0.5773502691896258f);
    } else if (t < O_VT) {
        int t2 = t - O_ET;
        int h = t2 / 54, c = t2 % 54;
#pragma unroll
        for (int d = 0; d < 3; ++d) {
            float v = in_b[24 + h * 3 + d];
            for (int j = 0; j < 12; ++j)
                v += in_w[(24 + h * 3 + d) * 12 + j] * card_emb[c * 12 + j];
            g_VT[t2 * 4 + d] = v;
        }
        g_VT[t2 * 4 + 3] = 1.0f;
    } else if (t < O_GS) {
        int id = t - O_VT;
        int tt = id >> 9, lane = (id >> 3) & 63, j = id & 7;
        int g = lane >> 4, n = lane & 15;
        int k = 8 * g + j, col = 16 * tt + n;
        float wv = (k < 12) ? gs_w1[col * 12 + k] : 0.f;
        short hi, lo;
        split_bf16(wv, hi, lo);
        int base = ((tt << 6) + lane) << 4;
        g_gsB[base + j] = hi;
        g_gsB[base + 8 + j] = lo;
    } else if (t < O_DP) {
        int id = t - O_GS;
        int st = id >> 9, lane = (id >> 3) & 63, j = id & 7;
        int s = st >> 2, tt = st & 3;
        int g = lane >> 4, n = lane & 15;
        int k = 32 * s + 8 * g + j, col = 16 * tt + n;
        float wv = (k < 54) ? dp_w1[col * 54 + k] : 0.f;
        short hi, lo;
        split_bf16(wv, hi, lo);
        int base = ((st << 6) + lane) << 4;
        g_dpB[base + j] = hi;
        g_dpB[base + 8 + j] = lo;
    } else if (t < O_CX) {
        int id = t - O_DP;
        int st = id >> 9, lane = (id >> 3) & 63, j = id & 7;
        int s = st >> 3, tt = st & 7;
        int g = lane >> 4, n = lane & 15;
        int k = 32 * s + 8 * g + j, hid = 16 * tt + n;
        float wv = ctxw(hid, k, ctx_w1, out_w, out_b);
        short hi, lo;
        split_bf16(wv, hi, lo);
        int base = ((st << 6) + lane) << 4;
        g_ctxB[base + j] = hi;
        g_ctxB[base + 8 + j] = lo;
    } else if (t < O_WT) {
        int id = t - O_CX;
        int st = id >> 9, lane = (id >> 3) & 63, j = id & 7;
        int s = st >> 1, tt = st & 1;
        int g = lane >> 4, n = lane & 15;
        int k = 32 * s + 8 * g + j, col = 16 * tt + n;
        float wv = 0.f;
        for (int i = 0; i < 128; ++i) wv += sc_w1[col * 140 + i] * ctx_w2[i * 128 + k];
        short hi, lo;
        split_bf16(wv, hi, lo);
        int base = ((st << 6) + lane) << 4;
        g_WtB[base + j] = hi;
        g_WtB[base + 8 + j] = lo;
    } else if (t < O_AB) {
        int t2 = t - O_WT;
        int a = t2 >> 5, j = t2 & 31;
        float arep[E];
#pragma unroll
        for (int k2 = 0; k2 < E; ++k2) arep[k2] = 0.f;
        float cnt = 0.f;
#pragma unroll
        for (int c = 0; c < KC; ++c) {
            int idx = aci[a * KC + c];
            if (idx != 0) {
                cnt += 1.f;
#pragma unroll
                for (int k2 = 0; k2 < E; ++k2) arep[k2] += card_emb[idx * E + k2];
            }
        }
        float inv = 1.f / fmaxf(cnt, 1.f);
        float s = sc_b1[j];
#pragma unroll
        for (int k2 = 0; k2 < E; ++k2) s += sc_w1[j * 140 + 128 + k2] * (arep[k2] * inv);
        for (int i = 0; i < 128; ++i) s += sc_w1[j * 140 + i] * ctx_b2[i];
        g_abias[t2] = s;
    }
}

// ============ Kernel A: table-driven attention + enemy -> g_feat ============
__global__ __launch_bounds__(1024) void featA_kernel(
    const int* __restrict__ hand_cards, const int* __restrict__ enemy_card,
    const int* __restrict__ hand_size, const float* __restrict__ enemy_emb) {
    __shared__ float sET[4 * 54 * 54];
    __shared__ __align__(16) float4 sV[4 * 54];
    __shared__ float sEN[54 * 12];

    int tid = threadIdx.x;
    for (int i = tid; i < 11664; i += 1024) sET[i] = g_ET[i];
    for (int i = tid; i < 864; i += 1024) ((float*)sV)[i] = g_VT[i];
    for (int i = tid; i < 648; i += 1024) sEN[i] = enemy_emb[i];
    __syncthreads();

    int q = tid & 3;
    int el = tid >> 2;
    int b = blockIdx.x * 256 + el;

    int hc[HS];
    {
        const int4* hp = (const int4*)(hand_cards + (size_t)b * HS);
        int4 h0 = hp[0], h1 = hp[1];
        hc[0] = h0.x; hc[1] = h0.y; hc[2] = h0.z; hc[3] = h0.w;
        hc[4] = h1.x; hc[5] = h1.y; hc[6] = h1.z; hc[7] = h1.w;
    }
    int ec = enemy_card[b];

    float4 vv[HS];
#pragma unroll
    for (int k = 0; k < HS; ++k) {
        float4 v = sV[q * 54 + hc[k]];
        if (hc[k] == 0) v = make_float4(0.f, 0.f, 0.f, 0.f);
        vv[k] = v;
    }

    const float* eb = sET + q * 2916;
    float a0 = 0.f, a1 = 0.f, a2 = 0.f;
#pragma unroll
    for (int p = 0; p < HS; ++p) {
        const float* er = eb + hc[p] * 54;
        float n0 = 0.f, n1 = 0.f, n2 = 0.f, nw = 0.f;
#pragma unroll
        for (int k = 0; k < HS; ++k) {
            float e = er[hc[k]];
            n0 += e * vv[k].x;
            n1 += e * vv[k].y;
            n2 += e * vv[k].z;
            nw += e * vv[k].w;
        }
        float rw = 1.f / fmaxf(nw, 1e-30f);
        a0 += n0 * rw; a1 += n1 * rw; a2 += n2 * rw;
    }
    float invlen = 1.f / fmaxf((float)hand_size[b], 1.f);
    float* fr = g_feat + (size_t)b * 32;
    fr[3 * q + 0] = a0 * invlen;
    fr[3 * q + 1] = a1 * invlen;
    fr[3 * q + 2] = a2 * invlen;
    fr[12 + 3 * q + 0] = sEN[ec * 12 + 3 * q + 0];
    fr[12 + 3 * q + 1] = sEN[ec * 12 + 3 * q + 1];
    fr[12 + 3 * q + 2] = sEN[ec * 12 + 3 * q + 2];
    if (q == 0) fr[24] = invlen;
}

#define FENCE() do { asm volatile("s_waitcnt lgkmcnt(0)" ::: "memory"); \
                     __builtin_amdgcn_sched_barrier(0); } while (0)

// ============ Kernel B: gs1/dp1 MFMA + VALU layer2 + ctx(K=64) + Wt + score ====
// 256 thr = 4 waves; each wave owns 32 elements (2 tiles of 16).
__global__ __launch_bounds__(256) void scoreB_kernel(
    const float* __restrict__ game_state, const float* __restrict__ discard,
    const int* __restrict__ num_valid, const float* __restrict__ gs_b1,
    const float* __restrict__ dp_b1, const float* __restrict__ gs_w2,
    const float* __restrict__ dp_w2, const float* __restrict__ gs_b2,
    const float* __restrict__ dp_b2, const float* __restrict__ ctx_b1,
    const float* __restrict__ sc_w2, const float* __restrict__ sc_b2,
    float* __restrict__ out) {
    // per-wave scratch: 32 elems x 132 floats; first 640 floats double as sFeat
    // (stride 20, cols 0..5 gs, 6..11 dp, 12..19 zero) before phase 4 reuses it.
    __shared__ __align__(16) float sU[4 * 4224];
    __shared__ __align__(16) float sAB[NA * 36];
    __shared__ __align__(16) float sW2[32];
    __shared__ __align__(16) float sGS2T[64 * 12];
    __shared__ __align__(16) float sDPW2T[64 * 12];
    __shared__ float sCB[128];
    __shared__ float sGSB[64];
    __shared__ float sDPB[64];

    int tid = threadIdx.x;
    for (int i = tid; i < NA * 36; i += 256) {
        int a = i / 36, c = i % 36;
        sAB[i] = (c < 32) ? g_abias[a * 32 + c] : 0.f;
    }
    for (int i = tid; i < 768; i += 256) {
        int r = i / 12, c = i % 12;
        sGS2T[i] = (c < 6) ? gs_w2[c * 64 + r] : 0.f;
        sDPW2T[i] = (c < 6) ? dp_w2[c * 64 + r] : 0.f;
    }
    if (tid < 32) sW2[tid] = sc_w2[tid];
    if (tid >= 32 && tid < 160) sCB[tid - 32] = ctx_b1[tid - 32];
    if (tid >= 160 && tid < 224) sGSB[tid - 160] = gs_b1[tid - 160];
    if (tid >= 192 && tid < 256) sDPB[tid - 192] = dp_b1[tid - 192];
    for (int i = tid; i < 4 * 640; i += 256) {
        int w2 = i / 640;
        sU[w2 * 4224 + (i % 640)] = 0.f;
    }
    __syncthreads();

    int lane = tid & 63;
    int w = tid >> 6;
    int n = lane & 15, g = lane >> 4;
    size_t eb0 = (size_t)blockIdx.x * 128 + (w << 5);
    float* SW = sU + w * 4224;
    float gb2 = (n < 6) ? gs_b2[n] : 0.f;
    float db2 = (n < 6) ? dp_b2[n] : 0.f;

    // ================= phase 1: gs1 + dp1 MFMA (both tiles) =================
    f32x4 gacc[2][4], dacc[2][4];
    {
        short8 gah[2], gal[2], dah0[2], dal0[2], dah1[2], dal1[2];
#pragma unroll
        for (int tau = 0; tau < 2; ++tau) {
            size_t bE = eb0 + 16 * tau + n;
            float xg[8];
#pragma unroll
            for (int j = 0; j < 8; ++j) {
                int k = 8 * g + j;
                xg[j] = (k < 12) ? game_state[bE * 12 + k] : 0.f;
            }
            split8(xg, gah[tau], gal[tau]);
            const float* drow = discard + bE * 54;
            float xa[8], xb[8];
            {
                const float2* p = (const float2*)(drow + 8 * g);
                float2 v0 = p[0], v1 = p[1], v2 = p[2], v3 = p[3];
                xa[0] = v0.x; xa[1] = v0.y; xa[2] = v1.x; xa[3] = v1.y;
                xa[4] = v2.x; xa[5] = v2.y; xa[6] = v3.x; xa[7] = v3.y;
            }
#pragma unroll
            for (int j = 0; j < 8; ++j) {
                int k = 32 + 8 * g + j;
                xb[j] = (k < 54) ? drow[k] : 0.f;
            }
            split8(xa, dah0[tau], dal0[tau]);
            split8(xb, dah1[tau], dal1[tau]);
        }
#pragma unroll
        for (int t = 0; t < 4; ++t) {
            const short8* bp = (const short8*)&g_gsB[((t << 6) + lane) << 4];
            short8 bh = bp[0], bl = bp[1];
            float bv = sGSB[16 * t + n];
#pragma unroll
            for (int tau = 0; tau < 2; ++tau) {
                f32x4 cc = {bv, bv, bv, bv};
                gacc[tau][t] = mfma3v(gah[tau], gal[tau], bh, bl, cc);
            }
        }
#pragma unroll
        for (int t = 0; t < 4; ++t) {
            const short8* b0 = (const short8*)&g_dpB[((t << 6) + lane) << 4];
            short8 b0h = b0[0], b0l = b0[1];
            const short8* b1 = (const short8*)&g_dpB[(((4 + t) << 6) + lane) << 4];
            short8 b1h = b1[0], b1l = b1[1];
            float bv = sDPB[16 * t + n];
#pragma unroll
            for (int tau = 0; tau < 2; ++tau) {
                f32x4 cc = {bv, bv, bv, bv};
                cc = mfma3v(dah0[tau], dal0[tau], b0h, b0l, cc);
                dacc[tau][t] = mfma3v(dah1[tau], dal1[tau], b1h, b1l, cc);
            }
        }
    }

    // ======= phase 2: layer-2 on VALU + quad-of-16 reduce -> sFeat =======
#pragma unroll
    for (int tau = 0; tau < 2; ++tau) {
        float pg[4][6], pd[4][6];
#pragma unroll
        for (int r = 0; r < 4; ++r)
#pragma unroll
            for (int c = 0; c < 6; ++c) { pg[r][c] = 0.f; pd[r][c] = 0.f; }
#pragma unroll
        for (int t = 0; t < 4; ++t) {
            const float* wg = &sGS2T[(16 * t + n) * 12];
            float4 wga = *(const float4*)wg;
            float2 wgb = *(const float2*)(wg + 4);
            const float* wd = &sDPW2T[(16 * t + n) * 12];
            float4 wda = *(const float4*)wd;
            float2 wdb = *(const float2*)(wd + 4);
#pragma unroll
            for (int r = 0; r < 4; ++r) {
                float hg = fmaxf(gacc[tau][t][r], 0.f);
                float hd = fmaxf(dacc[tau][t][r], 0.f);
                pg[r][0] += hg * wga.x; pg[r][1] += hg * wga.y; pg[r][2] += hg * wga.z;
                pg[r][3] += hg * wga.w; pg[r][4] += hg * wgb.x; pg[r][5] += hg * wgb.y;
                pd[r][0] += hd * wda.x; pd[r][1] += hd * wda.y; pd[r][2] += hd * wda.z;
                pd[r][3] += hd * wda.w; pd[r][4] += hd * wdb.x; pd[r][5] += hd * wdb.y;
            }
        }
#pragma unroll
        for (int r = 0; r < 4; ++r)
#pragma unroll
            for (int c = 0; c < 6; ++c) {
                float v = pg[r][c];
                v += __shfl_xor(v, 1, 64);
                v += __shfl_xor(v, 2, 64);
                v += __shfl_xor(v, 4, 64);
                v += __shfl_xor(v, 8, 64);
                pg[r][c] = v;
                float u = pd[r][c];
                u += __shfl_xor(u, 1, 64);
                u += __shfl_xor(u, 2, 64);
                u += __shfl_xor(u, 4, 64);
                u += __shfl_xor(u, 8, 64);
                pd[r][c] = u;
            }
        if (n < 6) {
#pragma unroll
            for (int r = 0; r < 4; ++r) {
                int e = 16 * tau + 4 * g + r;
                float gv = pg[r][0];
                gv = (n == 1) ? pg[r][1] : gv; gv = (n == 2) ? pg[r][2] : gv;
                gv = (n == 3) ? pg[r][3] : gv; gv = (n == 4) ? pg[r][4] : gv;
                gv = (n == 5) ? pg[r][5] : gv;
                float dv = pd[r][0];
                dv = (n == 1) ? pd[r][1] : dv; dv = (n == 2) ? pd[r][2] : dv;
                dv = (n == 3) ? pd[r][3] : dv; dv = (n == 4) ? pd[r][4] : dv;
                dv = (n == 5) ? pd[r][5] : dv;
                SW[e * 20 + n] = gv + gb2;
                SW[e * 20 + 6 + n] = dv + db2;
            }
        }
    }
    FENCE();

    // ================= phase 3: ctx1 MFMA (K=64, both tiles) =================
    f32x4 cacc[2][8];
#pragma unroll
    for (int tt = 0; tt < 8; ++tt) {
        float bv = sCB[16 * tt + n];
#pragma unroll
        for (int tau = 0; tau < 2; ++tau) {
            f32x4 cc = {bv, bv, bv, bv};
            cacc[tau][tt] = cc;
        }
    }
    {
        short8 ah[2], al[2];
#pragma unroll
        for (int tau = 0; tau < 2; ++tau) {
            size_t bE = eb0 + 16 * tau + n;
            const float4* fp = (const float4*)(g_feat + bE * 32 + 8 * g);
            float4 f0 = fp[0], f1 = fp[1];
            float ca[8] = {f0.x, f0.y, f0.z, f0.w, f1.x, f1.y, f1.z, f1.w};
            split8(ca, ah[tau], al[tau]);
        }
#pragma unroll
        for (int tt = 0; tt < 8; ++tt) {
            const short8* bp = (const short8*)&g_ctxB[((tt << 6) + lane) << 4];
            short8 bh = bp[0], bl = bp[1];
#pragma unroll
            for (int tau = 0; tau < 2; ++tau)
                cacc[tau][tt] = mfma3v(ah[tau], al[tau], bh, bl, cacc[tau][tt]);
        }
        // s=1: gs/dp feats from sFeat (g<2), zeros for g>=2
#pragma unroll
        for (int tau = 0; tau < 2; ++tau) {
            if (g < 2) {
                int e = 16 * tau + n;
                float xb[8];
#pragma unroll
                for (int j2 = 0; j2 < 4; ++j2) {
                    float2 v = *(const float2*)&SW[e * 20 + 8 * g + 2 * j2];
                    xb[2 * j2] = v.x;
                    xb[2 * j2 + 1] = v.y;
                }
                split8(xb, ah[tau], al[tau]);
            } else {
                short8 zz = {0, 0, 0, 0, 0, 0, 0, 0};
                ah[tau] = zz; al[tau] = zz;
            }
        }
#pragma unroll
        for (int tt = 0; tt < 8; ++tt) {
            const short8* bp = (const short8*)&g_ctxB[(((8 + tt) << 6) + lane) << 4];
            short8 bh = bp[0], bl = bp[1];
#pragma unroll
            for (int tau = 0; tau < 2; ++tau)
                cacc[tau][tt] = mfma3v(ah[tau], al[tau], bh, bl, cacc[tau][tt]);
        }
    }
    FENCE();

    // ========== phase 4: relu(h) -> SW rows [elem][hidden], stride 132 ==========
#pragma unroll
    for (int tau = 0; tau < 2; ++tau)
#pragma unroll
        for (int tt = 0; tt < 8; ++tt)
#pragma unroll
            for (int r = 0; r < 4; ++r)
                SW[(16 * tau + 4 * g + r) * 132 + 16 * tt + n] =
                    fmaxf(cacc[tau][tt][r], 0.f);
    FENCE();

    // ================= phase 5: Wt MFMA (K=128, both tiles) =================
    f32x4 uacc[2][2];
    {
        f32x4 z = {0.f, 0.f, 0.f, 0.f};
        uacc[0][0] = z; uacc[0][1] = z; uacc[1][0] = z; uacc[1][1] = z;
    }
#pragma unroll
    for (int s = 0; s < 4; ++s) {
        short8 ah[2], al[2];
#pragma unroll
        for (int tau = 0; tau < 2; ++tau) {
            const float4* ap = (const float4*)&SW[(16 * tau + n) * 132 + 32 * s + 8 * g];
            float4 a0 = ap[0], a1 = ap[1];
            float ha[8] = {a0.x, a0.y, a0.z, a0.w, a1.x, a1.y, a1.z, a1.w};
            split8(ha, ah[tau], al[tau]);
        }
#pragma unroll
        for (int t2 = 0; t2 < 2; ++t2) {
            const short8* bp = (const short8*)&g_WtB[(((s * 2 + t2) << 6) + lane) << 4];
            short8 bh = bp[0], bl = bp[1];
#pragma unroll
            for (int tau = 0; tau < 2; ++tau)
                uacc[tau][t2] = mfma3v(ah[tau], al[tau], bh, bl, uacc[tau][t2]);
        }
    }
    FENCE();

    // ================= phase 6: score layer =================
#pragma unroll
    for (int tau = 0; tau < 2; ++tau)
#pragma unroll
        for (int t2 = 0; t2 < 2; ++t2)
#pragma unroll
            for (int r = 0; r < 4; ++r)
                SW[(16 * tau + 4 * g + r) * 132 + 16 * t2 + n] = uacc[tau][t2][r];
    FENCE();
    int nva = num_valid[0];
    float sb2 = sc_b2[0];
#pragma unroll
    for (int tau = 0; tau < 2; ++tau) {
        float uu[32];
        {
            const float4* up = (const float4*)&SW[(16 * tau + n) * 132];
#pragma unroll
            for (int j8 = 0; j8 < 8; ++j8) {
                float4 v = up[j8];
                uu[4 * j8 + 0] = v.x; uu[4 * j8 + 1] = v.y;
                uu[4 * j8 + 2] = v.z; uu[4 * j8 + 3] = v.w;
            }
        }
        size_t bE = eb0 + 16 * tau + n;
#pragma unroll
        for (int t = 0; t < 5; ++t) {
            int a = g * 5 + t;
            const float4* ab = (const float4*)&sAB[a * 36];
            float s = sb2;
#pragma unroll
            for (int j8 = 0; j8 < 8; ++j8) {
                float4 av = ab[j8];
                float4 wv = ((const float4*)sW2)[j8];
                s += wv.x * fmaxf(uu[4 * j8 + 0] + av.x, 0.f);
                s += wv.y * fmaxf(uu[4 * j8 + 1] + av.y, 0.f);
                s += wv.z * fmaxf(uu[4 * j8 + 2] + av.z, 0.f);
                s += wv.w * fmaxf(uu[4 * j8 + 3] + av.w, 0.f);
            }
            out[bE * NA + a] = (a < nva) ? s : -1.0e8f;
        }
    }
}

extern "C" void kernel_launch(void* const* d_in, const int* in_sizes, int n_in,
                              void* d_out, int out_size, void* d_ws, size_t ws_size,
                              hipStream_t stream) {
    const int* hand_cards = (const int*)d_in[0];
    const float* game_state = (const float*)d_in[1];
    const float* discard = (const float*)d_in[2];
    const int* enemy_card = (const int*)d_in[3];
    const int* hand_size = (const int*)d_in[4];
    const int* aci = (const int*)d_in[5];
    const int* num_valid = (const int*)d_in[6];
    const float* card_emb = (const float*)d_in[7];
    const float* enemy_emb = (const float*)d_in[8];
    const float* in_w = (const float*)d_in[9];
    const float* in_b = (const float*)d_in[10];
    const float* out_w = (const float*)d_in[11];
    const float* out_b = (const float*)d_in[12];
    const float* gs_w1 = (const float*)d_in[13];
    const float* gs_b1 = (const float*)d_in[14];
    const float* gs_w2 = (const float*)d_in[15];
    const float* gs_b2 = (const float*)d_in[16];
    const float* dp_w1 = (const float*)d_in[17];
    const float* dp_b1 = (const float*)d_in[18];
    const float* dp_w2 = (const float*)d_in[19];
    const float* dp_b2 = (const float*)d_in[20];
    const float* ctx_w1 = (const float*)d_in[21];
    const float* ctx_b1 = (const float*)d_in[22];
    const float* ctx_w2 = (const float*)d_in[23];
    const float* ctx_b2 = (const float*)d_in[24];
    const float* sc_w1 = (const float*)d_in[25];
    const float* sc_b1 = (const float*)d_in[26];
    const float* sc_w2 = (const float*)d_in[27];
    const float* sc_b2 = (const float*)d_in[28];

    int B = in_sizes[0] / HS;

    precompute_kernel<<<121, 256, 0, stream>>>(
        card_emb, aci, ctx_w2, ctx_b2, sc_w1, sc_b1, in_w, in_b, ctx_w1,
        dp_w1, gs_w1, out_w, out_b);
    featA_kernel<<<B / 256, 1024, 0, stream>>>(hand_cards, enemy_card, hand_size,
                                               enemy_emb);
    scoreB_kernel<<<B / 128, 256, 0, stream>>>(
        game_state, discard, num_valid, gs_b1, dp_b1, gs_w2, dp_w2, gs_b2, dp_b2,
        ctx_b1, sc_w2, sc_b2, (float*)d_out);
}

// Round 9
// 56.823 us; speedup vs baseline: 1.3053x; 1.3053x over previous
//
#include <hip/hip_runtime.h>
#include <hip/hip_bf16.h>
#include <math.h>

#define HS 8
#define E 12
#define NA 20
#define KC 4

typedef float f32x4 __attribute__((ext_vector_type(4)));
typedef short short8 __attribute__((ext_vector_type(8)));

// ---------------- Precomputed, batch-independent tables ----------------
__device__ float g_ET[4 * 54 * 54];   // exp(q_h(c1)·k_h(c2)/sqrt(3))
__device__ float g_VT[4 * 54 * 4];    // per-head v vectors (v0,v1,v2,1)
__device__ float g_abias[NA * 32];    // per-action folded score bias
__device__ __align__(16) short g_gsB[4 * 64 * 16];    // gs_w1 B-frags [t][lane][8hi,8lo]
__device__ __align__(16) short g_dpB[8 * 64 * 16];    // dp_w1 B-frags [s*4+t][lane]
__device__ __align__(16) short g_ctxB[16 * 64 * 16];  // ctx W' B-frags [s*8+tt][lane], K=64
__device__ __align__(16) short g_WtB[8 * 64 * 16];    // folded Wt B-frags [s*2+t][lane]
// Inter-kernel features: [B][32] = attsum/len(12), enemy(12), 1/len, pads=0 (BSS zero)
__device__ __align__(16) float g_feat[65536 * 32];

__device__ __forceinline__ short bfh(float f) {
    return (short)__bfloat16_as_ushort(__float2bfloat16(f));
}
__device__ __forceinline__ void split_bf16(float f, short& hi, short& lo) {
    hi = bfh(f);
    float fh = __uint_as_float(((unsigned)(unsigned short)hi) << 16);
    lo = bfh(f - fh);
}
__device__ __forceinline__ void split8(const float* x, short8& hi, short8& lo) {
#pragma unroll
    for (int j = 0; j < 8; ++j) {
        short h, l;
        split_bf16(x[j], h, l);
        hi[j] = h; lo[j] = l;
    }
}

#define MFMA(a, b, c) __builtin_amdgcn_mfma_f32_16x16x32_bf16(a, b, c, 0, 0, 0)

__device__ __forceinline__ f32x4 mfma3v(short8 ah, short8 al, short8 bh, short8 bl,
                                        f32x4 c) {
    c = MFMA(ah, bh, c);
    c = MFMA(ah, bl, c);
    c = MFMA(al, bh, c);
    return c;
}

// ctx B'[k][hid], k in 0..63: out_w folded into k<12, invlen feat at k=24,
// gs layer-2 feats at k=32..37, dp at 38..43, zeros elsewhere.
__device__ float ctxw(int hid, int k, const float* ctx_w1, const float* out_w,
                      const float* out_b) {
    if (k < 12) {
        float s = 0.f;
        for (int i = 0; i < 12; ++i) s += ctx_w1[hid * 36 + i] * out_w[i * 12 + k];
        return s;
    } else if (k < 24) {
        return ctx_w1[hid * 36 + k];
    } else if (k == 24) {
        float s = 0.f;
        for (int i = 0; i < 12; ++i) s += ctx_w1[hid * 36 + i] * out_b[i];
        return 8.f * s;
    } else if (k < 32) {
        return 0.f;
    } else if (k < 44) {
        return ctx_w1[hid * 36 + 24 + (k - 32)];
    }
    return 0.f;
}

__global__ void precompute_kernel(const float* __restrict__ card_emb,
                                  const int* __restrict__ aci,
                                  const float* __restrict__ ctx_w2,
                                  const float* __restrict__ ctx_b2,
                                  const float* __restrict__ sc_w1,
                                  const float* __restrict__ sc_b1,
                                  const float* __restrict__ in_w,
                                  const float* __restrict__ in_b,
                                  const float* __restrict__ ctx_w1,
                                  const float* __restrict__ dp_w1,
                                  const float* __restrict__ gs_w1,
                                  const float* __restrict__ out_w,
                                  const float* __restrict__ out_b) {
    const int O_ET = 11664, O_VT = O_ET + 216, O_GS = O_VT + 2048, O_DP = O_GS + 4096;
    const int O_CX = O_DP + 8192, O_WT = O_CX + 4096, O_AB = O_WT + 640;
    int t = blockIdx.x * 256 + threadIdx.x;
    if (t < O_ET) {
        int h = t / 2916, rem = t % 2916;
        int c1 = rem / 54, c2 = rem % 54;
        float s = 0.f;
#pragma unroll
        for (int d = 0; d < 3; ++d) {
            float q = in_b[h * 3 + d], k = in_b[12 + h * 3 + d];
            for (int j = 0; j < 12; ++j) {
                q += in_w[(h * 3 + d) * 12 + j] * card_emb[c1 * 12 + j];
                k += in_w[(12 + h * 3 + d) * 12 + j] * card_emb[c2 * 12 + j];
            }
            s += q * k;
        }
        g_ET[t] = expf(s * 0.5773502691896258f);
    } else if (t < O_VT) {
        int t2 = t - O_ET;
        int h = t2 / 54, c = t2 % 54;
#pragma unroll
        for (int d = 0; d < 3; ++d) {
            float v = in_b[24 + h * 3 + d];
            for (int j = 0; j < 12; ++j)
                v += in_w[(24 + h * 3 + d) * 12 + j] * card_emb[c * 12 + j];
            g_VT[t2 * 4 + d] = v;
        }
        g_VT[t2 * 4 + 3] = 1.0f;
    } else if (t < O_GS) {
        int id = t - O_VT;
        int tt = id >> 9, lane = (id >> 3) & 63, j = id & 7;
        int g = lane >> 4, n = lane & 15;
        int k = 8 * g + j, col = 16 * tt + n;
        float wv = (k < 12) ? gs_w1[col * 12 + k] : 0.f;
        short hi, lo;
        split_bf16(wv, hi, lo);
        int base = ((tt << 6) + lane) << 4;
        g_gsB[base + j] = hi;
        g_gsB[base + 8 + j] = lo;
    } else if (t < O_DP) {
        int id = t - O_GS;
        int st = id >> 9, lane = (id >> 3) & 63, j = id & 7;
        int s = st >> 2, tt = st & 3;
        int g = lane >> 4, n = lane & 15;
        int k = 32 * s + 8 * g + j, col = 16 * tt + n;
        float wv = (k < 54) ? dp_w1[col * 54 + k] : 0.f;
        short hi, lo;
        split_bf16(wv, hi, lo);
        int base = ((st << 6) + lane) << 4;
        g_dpB[base + j] = hi;
        g_dpB[base + 8 + j] = lo;
    } else if (t < O_CX) {
        int id = t - O_DP;
        int st = id >> 9, lane = (id >> 3) & 63, j = id & 7;
        int s = st >> 3, tt = st & 7;
        int g = lane >> 4, n = lane & 15;
        int k = 32 * s + 8 * g + j, hid = 16 * tt + n;
        float wv = ctxw(hid, k, ctx_w1, out_w, out_b);
        short hi, lo;
        split_bf16(wv, hi, lo);
        int base = ((st << 6) + lane) << 4;
        g_ctxB[base + j] = hi;
        g_ctxB[base + 8 + j] = lo;
    } else if (t < O_WT) {
        int id = t - O_CX;
        int st = id >> 9, lane = (id >> 3) & 63, j = id & 7;
        int s = st >> 1, tt = st & 1;
        int g = lane >> 4, n = lane & 15;
        int k = 32 * s + 8 * g + j, col = 16 * tt + n;
        float wv = 0.f;
        for (int i = 0; i < 128; ++i) wv += sc_w1[col * 140 + i] * ctx_w2[i * 128 + k];
        short hi, lo;
        split_bf16(wv, hi, lo);
        int base = ((st << 6) + lane) << 4;
        g_WtB[base + j] = hi;
        g_WtB[base + 8 + j] = lo;
    } else if (t < O_AB) {
        int t2 = t - O_WT;
        int a = t2 >> 5, j = t2 & 31;
        float arep[E];
#pragma unroll
        for (int k2 = 0; k2 < E; ++k2) arep[k2] = 0.f;
        float cnt = 0.f;
#pragma unroll
        for (int c = 0; c < KC; ++c) {
            int idx = aci[a * KC + c];
            if (idx != 0) {
                cnt += 1.f;
#pragma unroll
                for (int k2 = 0; k2 < E; ++k2) arep[k2] += card_emb[idx * E + k2];
            }
        }
        float inv = 1.f / fmaxf(cnt, 1.f);
        float s = sc_b1[j];
#pragma unroll
        for (int k2 = 0; k2 < E; ++k2) s += sc_w1[j * 140 + 128 + k2] * (arep[k2] * inv);
        for (int i = 0; i < 128; ++i) s += sc_w1[j * 140 + i] * ctx_b2[i];
        g_abias[t2] = s;
    }
}

// ============ Kernel A: table-driven attention + enemy -> g_feat ============
__global__ __launch_bounds__(1024) void featA_kernel(
    const int* __restrict__ hand_cards, const int* __restrict__ enemy_card,
    const int* __restrict__ hand_size, const float* __restrict__ enemy_emb) {
    __shared__ float sET[4 * 54 * 54];
    __shared__ __align__(16) float4 sV[4 * 54];
    __shared__ float sEN[54 * 12];

    int tid = threadIdx.x;
    for (int i = tid; i < 11664; i += 1024) sET[i] = g_ET[i];
    for (int i = tid; i < 864; i += 1024) ((float*)sV)[i] = g_VT[i];
    for (int i = tid; i < 648; i += 1024) sEN[i] = enemy_emb[i];
    __syncthreads();

    int q = tid & 3;
    int el = tid >> 2;
    int b = blockIdx.x * 256 + el;

    int hc[HS];
    {
        const int4* hp = (const int4*)(hand_cards + (size_t)b * HS);
        int4 h0 = hp[0], h1 = hp[1];
        hc[0] = h0.x; hc[1] = h0.y; hc[2] = h0.z; hc[3] = h0.w;
        hc[4] = h1.x; hc[5] = h1.y; hc[6] = h1.z; hc[7] = h1.w;
    }
    int ec = enemy_card[b];

    float4 vv[HS];
#pragma unroll
    for (int k = 0; k < HS; ++k) {
        float4 v = sV[q * 54 + hc[k]];
        if (hc[k] == 0) v = make_float4(0.f, 0.f, 0.f, 0.f);
        vv[k] = v;
    }

    const float* eb = sET + q * 2916;
    float a0 = 0.f, a1 = 0.f, a2 = 0.f;
#pragma unroll
    for (int p = 0; p < HS; ++p) {
        const float* er = eb + hc[p] * 54;
        float n0 = 0.f, n1 = 0.f, n2 = 0.f, nw = 0.f;
#pragma unroll
        for (int k = 0; k < HS; ++k) {
            float e = er[hc[k]];
            n0 += e * vv[k].x;
            n1 += e * vv[k].y;
            n2 += e * vv[k].z;
            nw += e * vv[k].w;
        }
        float rw = 1.f / fmaxf(nw, 1e-30f);
        a0 += n0 * rw; a1 += n1 * rw; a2 += n2 * rw;
    }
    float invlen = 1.f / fmaxf((float)hand_size[b], 1.f);
    float* fr = g_feat + (size_t)b * 32;
    fr[3 * q + 0] = a0 * invlen;
    fr[3 * q + 1] = a1 * invlen;
    fr[3 * q + 2] = a2 * invlen;
    fr[12 + 3 * q + 0] = sEN[ec * 12 + 3 * q + 0];
    fr[12 + 3 * q + 1] = sEN[ec * 12 + 3 * q + 1];
    fr[12 + 3 * q + 2] = sEN[ec * 12 + 3 * q + 2];
    if (q == 0) fr[24] = invlen;
}

#define FENCE() do { asm volatile("s_waitcnt lgkmcnt(0)" ::: "memory"); \
                     __builtin_amdgcn_sched_barrier(0); } while (0)

// ============ Kernel B v3: single-tile, 8 waves/block, 3 fences ============
// 512 thr = 8 waves; each wave owns 16 elements. Per-wave LDS scratch 16x132.
// Fences only at: feats write->ctx read, hidden write->Wt read, u write->score.
__global__ __launch_bounds__(512) void scoreB_kernel(
    const float* __restrict__ game_state, const float* __restrict__ discard,
    const int* __restrict__ num_valid, const float* __restrict__ gs_b1,
    const float* __restrict__ dp_b1, const float* __restrict__ gs_w2,
    const float* __restrict__ dp_w2, const float* __restrict__ gs_b2,
    const float* __restrict__ dp_b2, const float* __restrict__ ctx_b1,
    const float* __restrict__ sc_w2, const float* __restrict__ sc_b2,
    float* __restrict__ out) {
    __shared__ __align__(16) float sU[8 * 2112];  // per-wave 16x132
    __shared__ __align__(16) float sAB[NA * 36];
    __shared__ __align__(16) float sW2[32];
    __shared__ __align__(16) float sGS2T[64 * 12];
    __shared__ __align__(16) float sDPW2T[64 * 12];
    __shared__ float sCB[128];
    __shared__ float sGSB[64];
    __shared__ float sDPB[64];

    int tid = threadIdx.x;
    for (int i = tid; i < NA * 36; i += 512) {
        int a = i / 36, c = i % 36;
        sAB[i] = (c < 32) ? g_abias[a * 32 + c] : 0.f;
    }
    for (int i = tid; i < 768; i += 512) {
        int r = i / 12, c = i % 12;
        sGS2T[i] = (c < 6) ? gs_w2[c * 64 + r] : 0.f;
        sDPW2T[i] = (c < 6) ? dp_w2[c * 64 + r] : 0.f;
    }
    if (tid < 32) sW2[tid] = sc_w2[tid];
    if (tid >= 32 && tid < 160) sCB[tid - 32] = ctx_b1[tid - 32];
    if (tid >= 160 && tid < 224) sGSB[tid - 160] = gs_b1[tid - 160];
    if (tid >= 224 && tid < 288) sDPB[tid - 224] = dp_b1[tid - 224];
    // zero the stride-20 feat region (16x20 floats) of each wave's scratch
    for (int i = tid; i < 8 * 320; i += 512) {
        int w2 = i / 320;
        sU[w2 * 2112 + (i % 320)] = 0.f;
    }
    __syncthreads();

    int lane = tid & 63;
    int w = tid >> 6;
    int n = lane & 15, g = lane >> 4;
    size_t eb0 = (size_t)blockIdx.x * 128 + (w << 4);
    size_t bE = eb0 + n;  // this lane's element (A-row / D-col)
    float* SW = sU + w * 2112;
    float gb2 = (n < 6) ? gs_b2[n] : 0.f;
    float db2 = (n < 6) ? dp_b2[n] : 0.f;

    // ================= phase 1: gs1 + dp1 MFMA =================
    f32x4 gacc[4], dacc[4];
    {
        short8 gah, gal, dah0, dal0, dah1, dal1;
        {
            float xg[8];
#pragma unroll
            for (int j = 0; j < 8; ++j) {
                int k = 8 * g + j;
                xg[j] = (k < 12) ? game_state[bE * 12 + k] : 0.f;
            }
            split8(xg, gah, gal);
            const float* drow = discard + bE * 54;
            float xa[8], xb[8];
            {
                const float2* p = (const float2*)(drow + 8 * g);
                float2 v0 = p[0], v1 = p[1], v2 = p[2], v3 = p[3];
                xa[0] = v0.x; xa[1] = v0.y; xa[2] = v1.x; xa[3] = v1.y;
                xa[4] = v2.x; xa[5] = v2.y; xa[6] = v3.x; xa[7] = v3.y;
            }
#pragma unroll
            for (int j = 0; j < 8; ++j) {
                int k = 32 + 8 * g + j;
                xb[j] = (k < 54) ? drow[k] : 0.f;
            }
            split8(xa, dah0, dal0);
            split8(xb, dah1, dal1);
        }
#pragma unroll
        for (int t = 0; t < 4; ++t) {
            const short8* bp = (const short8*)&g_gsB[((t << 6) + lane) << 4];
            float bv = sGSB[16 * t + n];
            f32x4 cc = {bv, bv, bv, bv};
            gacc[t] = mfma3v(gah, gal, bp[0], bp[1], cc);
        }
#pragma unroll
        for (int t = 0; t < 4; ++t) {
            const short8* b0 = (const short8*)&g_dpB[((t << 6) + lane) << 4];
            const short8* b1 = (const short8*)&g_dpB[(((4 + t) << 6) + lane) << 4];
            float bv = sDPB[16 * t + n];
            f32x4 cc = {bv, bv, bv, bv};
            cc = mfma3v(dah0, dal0, b0[0], b0[1], cc);
            dacc[t] = mfma3v(dah1, dal1, b1[0], b1[1], cc);
        }
    }

    // ======= phase 2: layer-2 on VALU + reduce over n -> SW stride-20 feats =======
    {
        float pg[4][6], pd[4][6];
#pragma unroll
        for (int r = 0; r < 4; ++r)
#pragma unroll
            for (int c = 0; c < 6; ++c) { pg[r][c] = 0.f; pd[r][c] = 0.f; }
#pragma unroll
        for (int t = 0; t < 4; ++t) {
            const float* wg = &sGS2T[(16 * t + n) * 12];
            float4 wga = *(const float4*)wg;
            float2 wgb = *(const float2*)(wg + 4);
            const float* wd = &sDPW2T[(16 * t + n) * 12];
            float4 wda = *(const float4*)wd;
            float2 wdb = *(const float2*)(wd + 4);
#pragma unroll
            for (int r = 0; r < 4; ++r) {
                float hg = fmaxf(gacc[t][r], 0.f);
                float hd = fmaxf(dacc[t][r], 0.f);
                pg[r][0] += hg * wga.x; pg[r][1] += hg * wga.y; pg[r][2] += hg * wga.z;
                pg[r][3] += hg * wga.w; pg[r][4] += hg * wgb.x; pg[r][5] += hg * wgb.y;
                pd[r][0] += hd * wda.x; pd[r][1] += hd * wda.y; pd[r][2] += hd * wda.z;
                pd[r][3] += hd * wda.w; pd[r][4] += hd * wdb.x; pd[r][5] += hd * wdb.y;
            }
        }
#pragma unroll
        for (int r = 0; r < 4; ++r)
#pragma unroll
            for (int c = 0; c < 6; ++c) {
                float v = pg[r][c];
                v += __shfl_xor(v, 1, 64);
                v += __shfl_xor(v, 2, 64);
                v += __shfl_xor(v, 4, 64);
                v += __shfl_xor(v, 8, 64);
                pg[r][c] = v;
                float u = pd[r][c];
                u += __shfl_xor(u, 1, 64);
                u += __shfl_xor(u, 2, 64);
                u += __shfl_xor(u, 4, 64);
                u += __shfl_xor(u, 8, 64);
                pd[r][c] = u;
            }
        if (n < 6) {
#pragma unroll
            for (int r = 0; r < 4; ++r) {
                int e = 4 * g + r;
                float gv = pg[r][0];
                gv = (n == 1) ? pg[r][1] : gv; gv = (n == 2) ? pg[r][2] : gv;
                gv = (n == 3) ? pg[r][3] : gv; gv = (n == 4) ? pg[r][4] : gv;
                gv = (n == 5) ? pg[r][5] : gv;
                float dv = pd[r][0];
                dv = (n == 1) ? pd[r][1] : dv; dv = (n == 2) ? pd[r][2] : dv;
                dv = (n == 3) ? pd[r][3] : dv; dv = (n == 4) ? pd[r][4] : dv;
                dv = (n == 5) ? pd[r][5] : dv;
                SW[e * 20 + n] = gv + gb2;
                SW[e * 20 + 6 + n] = dv + db2;
            }
        }
    }
    FENCE();

    // ================= phase 3: ctx1 MFMA (K=64) =================
    f32x4 cacc[8];
#pragma unroll
    for (int tt = 0; tt < 8; ++tt) {
        float bv = sCB[16 * tt + n];
        f32x4 cc = {bv, bv, bv, bv};
        cacc[tt] = cc;
    }
    {
        short8 ah, al;
        {
            const float4* fp = (const float4*)(g_feat + bE * 32 + 8 * g);
            float4 f0 = fp[0], f1 = fp[1];
            float ca[8] = {f0.x, f0.y, f0.z, f0.w, f1.x, f1.y, f1.z, f1.w};
            split8(ca, ah, al);
        }
#pragma unroll
        for (int tt = 0; tt < 8; ++tt) {
            const short8* bp = (const short8*)&g_ctxB[((tt << 6) + lane) << 4];
            cacc[tt] = mfma3v(ah, al, bp[0], bp[1], cacc[tt]);
        }
        // s=1 half: k=32..63 -> gs/dp feats from SW (g<2), zeros g>=2
        if (g < 2) {
            float xb[8];
#pragma unroll
            for (int j2 = 0; j2 < 4; ++j2) {
                float2 v = *(const float2*)&SW[n * 20 + 8 * g + 2 * j2];
                xb[2 * j2] = v.x;
                xb[2 * j2 + 1] = v.y;
            }
            split8(xb, ah, al);
        } else {
            short8 zz = {0, 0, 0, 0, 0, 0, 0, 0};
            ah = zz; al = zz;
        }
#pragma unroll
        for (int tt = 0; tt < 8; ++tt) {
            const short8* bp = (const short8*)&g_ctxB[(((8 + tt) << 6) + lane) << 4];
            cacc[tt] = mfma3v(ah, al, bp[0], bp[1], cacc[tt]);
        }
    }

    // ========== phase 4: relu(h) -> SW [elem][hidden], stride 132, ONE fence ====
#pragma unroll
    for (int tt = 0; tt < 8; ++tt)
#pragma unroll
        for (int r = 0; r < 4; ++r)
            SW[(4 * g + r) * 132 + 16 * tt + n] = fmaxf(cacc[tt][r], 0.f);
    FENCE();

    // ================= phase 5: Wt MFMA (K=128) =================
    f32x4 uacc[2];
    {
        f32x4 z = {0.f, 0.f, 0.f, 0.f};
        uacc[0] = z; uacc[1] = z;
    }
#pragma unroll
    for (int s = 0; s < 4; ++s) {
        const float4* ap = (const float4*)&SW[n * 132 + 32 * s + 8 * g];
        float4 a0 = ap[0], a1 = ap[1];
        float ha[8] = {a0.x, a0.y, a0.z, a0.w, a1.x, a1.y, a1.z, a1.w};
        short8 ah, al;
        split8(ha, ah, al);
#pragma unroll
        for (int t2 = 0; t2 < 2; ++t2) {
            const short8* bp = (const short8*)&g_WtB[(((s * 2 + t2) << 6) + lane) << 4];
            uacc[t2] = mfma3v(ah, al, bp[0], bp[1], uacc[t2]);
        }
    }

    // ================= phase 6: u transpose + score =================
#pragma unroll
    for (int t2 = 0; t2 < 2; ++t2)
#pragma unroll
        for (int r = 0; r < 4; ++r)
            SW[(4 * g + r) * 132 + 16 * t2 + n] = uacc[t2][r];
    FENCE();
    {
        float uu[32];
        {
            const float4* up = (const float4*)&SW[n * 132];
#pragma unroll
            for (int j8 = 0; j8 < 8; ++j8) {
                float4 v = up[j8];
                uu[4 * j8 + 0] = v.x; uu[4 * j8 + 1] = v.y;
                uu[4 * j8 + 2] = v.z; uu[4 * j8 + 3] = v.w;
            }
        }
        int nva = num_valid[0];
        float sb2 = sc_b2[0];
#pragma unroll
        for (int t = 0; t < 5; ++t) {
            int a = g * 5 + t;
            const float4* ab = (const float4*)&sAB[a * 36];
            float s = sb2;
#pragma unroll
            for (int j8 = 0; j8 < 8; ++j8) {
                float4 av = ab[j8];
                float4 wv = ((const float4*)sW2)[j8];
                s += wv.x * fmaxf(uu[4 * j8 + 0] + av.x, 0.f);
                s += wv.y * fmaxf(uu[4 * j8 + 1] + av.y, 0.f);
                s += wv.z * fmaxf(uu[4 * j8 + 2] + av.z, 0.f);
                s += wv.w * fmaxf(uu[4 * j8 + 3] + av.w, 0.f);
            }
            out[bE * NA + a] = (a < nva) ? s : -1.0e8f;
        }
    }
}

extern "C" void kernel_launch(void* const* d_in, const int* in_sizes, int n_in,
                              void* d_out, int out_size, void* d_ws, size_t ws_size,
                              hipStream_t stream) {
    const int* hand_cards = (const int*)d_in[0];
    const float* game_state = (const float*)d_in[1];
    const float* discard = (const float*)d_in[2];
    const int* enemy_card = (const int*)d_in[3];
    const int* hand_size = (const int*)d_in[4];
    const int* aci = (const int*)d_in[5];
    const int* num_valid = (const int*)d_in[6];
    const float* card_emb = (const float*)d_in[7];
    const float* enemy_emb = (const float*)d_in[8];
    const float* in_w = (const float*)d_in[9];
    const float* in_b = (const float*)d_in[10];
    const float* out_w = (const float*)d_in[11];
    const float* out_b = (const float*)d_in[12];
    const float* gs_w1 = (const float*)d_in[13];
    const float* gs_b1 = (const float*)d_in[14];
    const float* gs_w2 = (const float*)d_in[15];
    const float* gs_b2 = (const float*)d_in[16];
    const float* dp_w1 = (const float*)d_in[17];
    const float* dp_b1 = (const float*)d_in[18];
    const float* dp_w2 = (const float*)d_in[19];
    const float* dp_b2 = (const float*)d_in[20];
    const float* ctx_w1 = (const float*)d_in[21];
    const float* ctx_b1 = (const float*)d_in[22];
    const float* ctx_w2 = (const float*)d_in[23];
    const float* ctx_b2 = (const float*)d_in[24];
    const float* sc_w1 = (const float*)d_in[25];
    const float* sc_b1 = (const float*)d_in[26];
    const float* sc_w2 = (const float*)d_in[27];
    const float* sc_b2 = (const float*)d_in[28];

    int B = in_sizes[0] / HS;

    precompute_kernel<<<121, 256, 0, stream>>>(
        card_emb, aci, ctx_w2, ctx_b2, sc_w1, sc_b1, in_w, in_b, ctx_w1,
        dp_w1, gs_w1, out_w, out_b);
    featA_kernel<<<B / 256, 1024, 0, stream>>>(hand_cards, enemy_card, hand_size,
                                               enemy_emb);
    scoreB_kernel<<<B / 128, 512, 0, stream>>>(
        game_state, discard, num_valid, gs_b1, dp_b1, gs_w2, dp_w2, gs_b2, dp_b2,
        ctx_b1, sc_w2, sc_b2, (float*)d_out);
}